// Round 3
// baseline (381.283 us; speedup 1.0000x reference)
//
#include <hip/hip_runtime.h>
#include <hip/hip_bf16.h>

#define HWPX 4096

typedef __attribute__((ext_vector_type(8))) short short8v;
typedef __attribute__((ext_vector_type(4))) float f32x4;
#define MFMA(a,b,c) __builtin_amdgcn_mfma_f32_16x16x32_bf16(a,b,c,0,0,0)

__device__ __forceinline__ float sigf(float x){ return 1.0f/(1.0f+__expf(-x)); }
__device__ __forceinline__ unsigned short f2bf(float f){
  __hip_bfloat16 h = __float2bfloat16(f);
  unsigned short u; __builtin_memcpy(&u, &h, sizeof(u)); return u;
}
__device__ __forceinline__ float bf2f(unsigned short u){
  return __uint_as_float(((unsigned)u)<<16);
}
__device__ __forceinline__ void gl2lds16(const void* g, void* l){
  __builtin_amdgcn_global_load_lds((const __attribute__((address_space(1))) void*)g,
                                   (__attribute__((address_space(3))) void*)l, 16, 0, 0);
}

// ---------------- K0: weight images (bf16, fragment-ready, unswizzled) + x11 = softmax(gn_b) -----
// wimg: [q2][conv2][tap9][co64][ci32] bf16 ; wcimg: [o64][ch128] bf16
__global__ __launch_bounds__(256) void k_prep(const float* wb1, const float* wb2,
                                              const float* wcat, const float* gnb,
                                              unsigned short* wimg, unsigned short* wcimg,
                                              float* x11){
  int tid = threadIdx.x;
  for (int idx = tid; idx < 73728; idx += 256){
    int q    = idx / 36864;
    int rem  = idx % 36864;
    int conv = rem / 18432;
    int rem2 = rem % 18432;
    int tap  = rem2 / 2048;
    int rem3 = rem2 % 2048;
    int co   = rem3 / 32;
    int cil  = rem3 % 32;
    int ci = q*32 + cil;
    const float* src = conv ? wb2 : wb1;
    float v = src[(co*64 + ci)*9 + tap];
    wimg[((q*18 + conv*9 + tap)*64 + co)*32 + cil] = f2bf(v);
  }
  for (int idx = tid; idx < 8192; idx += 256){
    wcimg[idx] = f2bf(wcat[idx]);
  }
  if (tid < 64){
    float g = gnb[tid];
    float m = g;
    for (int s=32; s; s>>=1) m = fmaxf(m, __shfl_xor(m, s));
    float e = __expf(g-m);
    float se = e;
    for (int s=32; s; s>>=1) se += __shfl_xor(se, s);
    x11[tid] = e/se;
  }
}

// ---------------- K1: x -> bf16 slotted layout xb[g*64+row][slot][col][e8] + row/col means --------
__global__ __launch_bounds__(256) void k_rc(const float* __restrict__ x,
                                            unsigned short* __restrict__ xb,
                                            float* __restrict__ hwbuf){
  int blk = blockIdx.x;          // g*8 + slot
  int g = blk >> 3, slot = blk & 7;
  int tid = threadIdx.x;
  int col = tid & 63, wid = tid >> 6;
  __shared__ float rsm[8*64];
  __shared__ float csm[4*8*64];
  float colacc[8] = {0,0,0,0,0,0,0,0};
  const float* xbase = x + ((size_t)(g*64 + slot*8))*HWPX;
  for (int p=0;p<16;++p){
    int r = wid + 4*p;
    const float* src = xbase + r*64 + col;
    float v[8];
    #pragma unroll
    for (int e=0;e<8;e++) v[e] = src[(size_t)e*HWPX];
    unsigned pk[4];
    #pragma unroll
    for (int j=0;j<4;j++) pk[j] = (unsigned)f2bf(v[2*j]) | ((unsigned)f2bf(v[2*j+1])<<16);
    f32x4 st; __builtin_memcpy(&st, pk, 16);
    *(f32x4*)((char*)xb + (((size_t)(g*64+r))*8 + slot)*1024 + col*16) = st;
    #pragma unroll
    for (int e=0;e<8;e++){
      float s = v[e];
      s += __shfl_xor(s,1); s += __shfl_xor(s,2); s += __shfl_xor(s,4);
      s += __shfl_xor(s,8); s += __shfl_xor(s,16); s += __shfl_xor(s,32);
      if ((tid&63)==0) rsm[e*64+r] = s;
      colacc[e] += v[e];
    }
  }
  #pragma unroll
  for (int e=0;e<8;e++) csm[(wid*8+e)*64+col] = colacc[e];
  __syncthreads();
  float* hb = hwbuf + ((size_t)(g*64 + slot*8))*128;
  for (int idx=tid; idx<512; idx+=256){
    int e = idx>>6, r = idx&63;
    hb[e*128 + r] = rsm[e*64+r] * (1.0f/64.0f);
  }
  for (int idx=tid; idx<512; idx+=256){
    int e = idx>>6, c2 = idx&63;
    float s = csm[(0*8+e)*64+c2] + csm[(1*8+e)*64+c2] + csm[(2*8+e)*64+c2] + csm[(3*8+e)*64+c2];
    hb[e*128 + 64 + c2] = s * (1.0f/64.0f);
  }
}

// ---------------- K2: hw = sigmoid(w_hw @ hw + b_hw) -> sigbuf[bg][o][128] ----------------
__global__ __launch_bounds__(256) void k_hwmm(const float* hwbuf, const float* whw,
                                              const float* bhw, float* sigbuf){
  int g = blockIdx.x;
  __shared__ float hl[64*128];
  int tid = threadIdx.x;
  const float* src = hwbuf + (size_t)g*8192;
  for (int i = tid; i < 2048; i += 256) ((float4*)hl)[i] = ((const float4*)src)[i];
  __syncthreads();
  int p  = tid & 127;
  int o0 = (tid >> 7) * 32;
  float acc[32];
  #pragma unroll
  for (int k=0;k<32;k++) acc[k] = bhw[o0+k];
  for (int i=0;i<64;i++){
    float v = hl[i*128+p];
    #pragma unroll
    for (int k=0;k<32;k++) acc[k] = fmaf(whw[(o0+k)*64+i], v, acc[k]);
  }
  float* dst = sigbuf + (size_t)g*8192;
  #pragma unroll
  for (int k=0;k<32;k++) dst[(o0+k)*128+p] = sigf(acc[k]);
}

// ---------------- K3: gate + GroupNorm -> x1 (bf16) ----------------
__global__ __launch_bounds__(256) void k_gate(const float* x, const float* sigbuf,
                                              const float* gnw, const float* gnb,
                                              unsigned short* x1buf){
  int blk = blockIdx.x;                      // g*64 + c
  int g = blk >> 6, c = blk & 63;
  const float* px = x + (size_t)blk*HWPX;
  __shared__ float sg[128];
  __shared__ float rs[4], rs2[4];
  int tid = threadIdx.x;
  if (tid < 128) sg[tid] = sigbuf[(size_t)g*8192 + c*128 + tid];
  __syncthreads();
  float gate[16];
  float s = 0.f, s2 = 0.f;
  #pragma unroll
  for (int k=0;k<4;k++){
    int i = tid + 256*k;
    float4 v = ((const float4*)px)[i];
    int p = i*4; int r = p>>6, col = p&63;
    float sh = sg[r];
    float g0 = v.x*sh*sg[64+col+0];
    float g1 = v.y*sh*sg[64+col+1];
    float g2 = v.z*sh*sg[64+col+2];
    float g3 = v.w*sh*sg[64+col+3];
    gate[4*k+0]=g0; gate[4*k+1]=g1; gate[4*k+2]=g2; gate[4*k+3]=g3;
    s  += g0+g1+g2+g3;
    s2 += g0*g0+g1*g1+g2*g2+g3*g3;
  }
  for (int sh=32; sh; sh>>=1){ s += __shfl_xor(s, sh); s2 += __shfl_xor(s2, sh); }
  int wid = tid >> 6, lane = tid & 63;
  if (lane == 0){ rs[wid]=s; rs2[wid]=s2; }
  __syncthreads();
  float tot  = rs[0]+rs[1]+rs[2]+rs[3];
  float tot2 = rs2[0]+rs2[1]+rs2[2]+rs2[3];
  float mu  = tot*(1.f/4096.f);
  float var = tot2*(1.f/4096.f) - mu*mu;
  float scale = rsqrtf(var + 1e-5f) * gnw[c];
  float shift = gnb[c] - mu*scale;
  unsigned short* dst = x1buf + (size_t)blk*HWPX;
  #pragma unroll
  for (int k=0;k<4;k++){
    int p = 4*(tid + 256*k);
    ushort4 st;
    st.x = f2bf(gate[4*k+0]*scale + shift);
    st.y = f2bf(gate[4*k+1]*scale + shift);
    st.z = f2bf(gate[4*k+2]*scale + shift);
    st.w = f2bf(gate[4*k+3]*scale + shift);
    *(ushort4*)(dst + p) = st;
  }
}

// ---------------- K4: fused MFMA conv3x3(d=1)+conv3x3(d=2)+PReLU+residual + 1x1 cat conv ----------
// grid = 128 g * 8 strips ; 512 threads. Input staged from bf16 xb via global_load_lds (both q
// chunks, one barrier). Weights read per-lane direct from global (L2-resident). LDS: 2x52224 input
// buffers, reused as 128KiB BR in epilogue. Dynamic LDS = 131072 -> 1 block/CU.
__global__ __launch_bounds__(512, 2) void k_convcat(const float* __restrict__ x,
                                                    const unsigned short* __restrict__ xb,
                                                    const char* __restrict__ wgl,
                                                    const char* __restrict__ wcgl,
                                                    const float* __restrict__ bb1,
                                                    const float* __restrict__ bb2,
                                                    const float* __restrict__ a1p,
                                                    const float* __restrict__ a2p,
                                                    const float* __restrict__ bcat,
                                                    unsigned short* __restrict__ x2buf,
                                                    float* __restrict__ x2mean){
  extern __shared__ char smem[];
  const int tid = threadIdx.x;
  const int g = blockIdx.x >> 3;
  const int strip = blockIdx.x & 7;
  const int r0 = strip*8;
  const int w = tid >> 6;
  const int lane = tid & 63;
  const int l15 = lane & 15;
  const int lg = lane >> 4;
  const int conv = w >> 2;
  const int c0 = (w&3)*16;
  const int dil = conv + 1;

  // zero pad columns {0,1,66,67} of both input buffers
  if (tid < 384){
    int b = tid / 192, t = tid % 192;
    int row = t >> 4, rem = t & 15, slot = rem >> 2, pc = rem & 3;
    int colp = (pc<2)? pc : pc+64;
    f32x4 z = {0.f,0.f,0.f,0.f};
    *(f32x4*)(smem + b*52224 + ((row*4+slot)*68 + colp)*16) = z;
  }
  // stage both q chunks (each: 12 rows x 4 slots, 1024B segments) via global_load_lds
  #pragma unroll
  for (int q=0;q<2;++q){
    #pragma unroll
    for (int i=0;i<6;++i){
      int seg = w*6 + i;
      int row = seg >> 2, slot = seg & 3;
      int rg = r0 - 2 + row;
      char* dst = smem + q*52224 + seg*1088 + 32;
      if ((unsigned)rg < 64u){
        const char* src = (const char*)xb + ((((size_t)(g*64+rg))*8 + q*4 + slot)<<10) + lane*16;
        gl2lds16(src, dst);
      } else {
        f32x4 z = {0.f,0.f,0.f,0.f};
        *(f32x4*)(dst + lane*16) = z;
      }
    }
  }

  f32x4 acc[4][8];
  #pragma unroll
  for (int m=0;m<4;m++)
    #pragma unroll
    for (int r=0;r<8;r++)
      acc[m][r] = (f32x4){0.f,0.f,0.f,0.f};

  __syncthreads();

  const int in_lane = lg*1088 + ((c0 + 2 + l15)<<4);
  #pragma unroll
  for (int q=0;q<2;++q){
    const char* inb = smem + q*52224 + in_lane - 32;
    const char* wq = wgl + (size_t)((q*18 + conv*9)*64)*64 + l15*64 + lg*16;
    #pragma unroll
    for (int tap=0;tap<9;++tap){
      const int dy = tap/3 - 1, dx = tap%3 - 1;
      const int off_tap = (dy*dil+2)*4352 + (dx*dil+2)*16;
      const char* wp = wq + tap*4096;
      short8v A0 = *(const short8v*)(wp);
      short8v A1 = *(const short8v*)(wp + 1024);
      short8v A2 = *(const short8v*)(wp + 2048);
      short8v A3 = *(const short8v*)(wp + 3072);
      const char* ib = inb + off_tap;
      #pragma unroll
      for (int r=0;r<8;++r){
        short8v B = *(const short8v*)(ib + r*4352);
        acc[0][r] = MFMA(A0, B, acc[0][r]);
        acc[1][r] = MFMA(A1, B, acc[1][r]);
        acc[2][r] = MFMA(A2, B, acc[2][r]);
        acc[3][r] = MFMA(A3, B, acc[3][r]);
      }
    }
  }
  __syncthreads();

  // epilogue: bias + PReLU + residual(x, f32) -> BR[px512][ch128 swz] bf16 (packed ushort4 writes)
  char* BR = smem;
  {
    const float alpha = conv ? a2p[0] : a1p[0];
    const float* bbp = conv ? bb2 : bb1;
    #pragma unroll
    for (int m=0;m<4;m++){
      int cob = m*16 + lg*4;
      float b0=bbp[cob], b1=bbp[cob+1], b2=bbp[cob+2], b3=bbp[cob+3];
      int ch = conv*64 + cob;
      int slotswz = ((ch>>3) ^ (l15&7)) << 4;
      int bytelo  = (ch&7) << 1;
      const float* resp = x + ((size_t)(g*64 + cob))*HWPX + r0*64 + c0 + l15;
      #pragma unroll
      for (int r=0;r<8;r++){
        float v0 = acc[m][r][0]+b0; v0 = (v0>=0.f? v0 : alpha*v0) + resp[r*64];
        float v1 = acc[m][r][1]+b1; v1 = (v1>=0.f? v1 : alpha*v1) + resp[r*64 + HWPX];
        float v2 = acc[m][r][2]+b2; v2 = (v2>=0.f? v2 : alpha*v2) + resp[r*64 + 2*HWPX];
        float v3 = acc[m][r][3]+b3; v3 = (v3>=0.f? v3 : alpha*v3) + resp[r*64 + 3*HWPX];
        ushort4 pkv; pkv.x=f2bf(v0); pkv.y=f2bf(v1); pkv.z=f2bf(v2); pkv.w=f2bf(v3);
        int pxl = r*64 + c0 + l15;
        *(ushort4*)(BR + pxl*256 + slotswz + bytelo) = pkv;
      }
    }
  }
  __syncthreads();

  // cat 1x1 conv: x2[o][px] = sum_ch wcat[o][ch]*br[ch][px] (+bcat at store); A direct from global
  {
    f32x4 c2[4][4];
    #pragma unroll
    for (int m=0;m<4;m++)
      #pragma unroll
      for (int nf=0;nf<4;nf++)
        c2[m][nf] = (f32x4){0.f,0.f,0.f,0.f};

    #pragma unroll
    for (int kc=0;kc<4;kc++){
      short8v Af[4];
      #pragma unroll
      for (int m=0;m<4;m++)
        Af[m] = *(const short8v*)(wcgl + (size_t)((m*16+l15)*128 + kc*32 + lg*8)*2);
      #pragma unroll
      for (int nf=0;nf<4;nf++){
        int pxl = w*64 + nf*16 + l15;
        short8v Bc = *(const short8v*)(BR + pxl*256 + (((kc*4+lg) ^ (l15&7))<<4));
        c2[0][nf] = MFMA(Af[0], Bc, c2[0][nf]);
        c2[1][nf] = MFMA(Af[1], Bc, c2[1][nf]);
        c2[2][nf] = MFMA(Af[2], Bc, c2[2][nf]);
        c2[3][nf] = MFMA(Af[3], Bc, c2[3][nf]);
      }
    }
    #pragma unroll
    for (int m=0;m<4;m++){
      #pragma unroll
      for (int reg=0;reg<4;reg++){
        int o = m*16 + lg*4 + reg;
        float bc = bcat[o];
        float s = 0.f;
        unsigned short* xp = x2buf + ((size_t)(g*64 + o))*HWPX + strip*512 + w*64 + l15;
        #pragma unroll
        for (int nf=0;nf<4;nf++){
          float v = c2[m][nf][reg];
          s += v;
          xp[nf*16] = f2bf(v + bc);
        }
        #pragma unroll
        for (int off=1; off<16; off<<=1) s += __shfl_xor(s, off);
        if (l15 == 0) atomicAdd(&x2mean[g*64 + o], s);
      }
    }
  }
}

// ---------------- K5: x21 = softmax(mean(x2)) from accumulated sums ----------------
__global__ __launch_bounds__(64) void k_x21s(const float* x2mean, const float* bcat, float* x21){
  int g = blockIdx.x;
  int o = threadIdx.x;
  float mean = x2mean[g*64 + o] * (1.f/4096.f) + bcat[o];
  float mx = mean;
  for (int s=32; s; s>>=1) mx = fmaxf(mx, __shfl_xor(mx, s));
  float e = __expf(mean - mx);
  float se = e;
  for (int s=32; s; s>>=1) se += __shfl_xor(se, s);
  x21[g*64 + o] = e/se;
}

// ---------------- K6: weights = x11.x2 + x21.x1 ; out = gx * sigmoid(weights) ----------------
__global__ __launch_bounds__(256) void k_final(const float* x, const unsigned short* x1buf,
                                               const unsigned short* x2buf, const float* x11,
                                               const float* x21, float* out){
  int blk = blockIdx.x;                 // g*4 + strip
  int g = blk >> 2;
  int tid = threadIdx.x;
  int p0 = (blk & 3)*1024 + tid*4;
  __shared__ float wa[64], wb[64];
  if (tid < 64){ wa[tid] = x11[tid]; wb[tid] = x21[g*64+tid]; }
  __syncthreads();
  float w0=0.f,w1=0.f,w2=0.f,w3=0.f;
  const unsigned short* x1p = x1buf + (size_t)g*64*HWPX + p0;
  const unsigned short* x2p = x2buf + (size_t)g*64*HWPX + p0;
  for (int c=0;c<64;c++){
    ushort4 u2 = *(const ushort4*)(x2p + (size_t)c*HWPX);
    ushort4 u1 = *(const ushort4*)(x1p + (size_t)c*HWPX);
    float A = wa[c], Bw = wb[c];
    w0 += A*bf2f(u2.x) + Bw*bf2f(u1.x);
    w1 += A*bf2f(u2.y) + Bw*bf2f(u1.y);
    w2 += A*bf2f(u2.z) + Bw*bf2f(u1.z);
    w3 += A*bf2f(u2.w) + Bw*bf2f(u1.w);
  }
  float s0 = sigf(w0), s1 = sigf(w1), s2 = sigf(w2), s3 = sigf(w3);
  const float* xg = x + (size_t)g*64*HWPX + p0;
  float* op = out + (size_t)g*64*HWPX + p0;
  for (int c=0;c<64;c++){
    float4 v = *(const float4*)(xg + (size_t)c*HWPX);
    float4 r; r.x = v.x*s0; r.y = v.y*s1; r.z = v.z*s2; r.w = v.w*s3;
    *(float4*)(op + (size_t)c*HWPX) = r;
  }
}

extern "C" void kernel_launch(void* const* d_in, const int* in_sizes, int n_in,
                              void* d_out, int out_size, void* d_ws, size_t ws_size,
                              hipStream_t stream) {
  const float* x     = (const float*)d_in[0];
  const float* w_hw  = (const float*)d_in[1];
  const float* b_hw  = (const float*)d_in[2];
  const float* gn_w  = (const float*)d_in[3];
  const float* gn_b  = (const float*)d_in[4];
  const float* w_b1  = (const float*)d_in[5];
  const float* b_b1  = (const float*)d_in[6];
  const float* a_b1  = (const float*)d_in[7];
  const float* w_b2  = (const float*)d_in[8];
  const float* b_b2  = (const float*)d_in[9];
  const float* a_b2  = (const float*)d_in[10];
  const float* w_cat = (const float*)d_in[11];
  const float* b_cat = (const float*)d_in[12];

  char* ws = (char*)d_ws;
  unsigned short* wimg  = (unsigned short*)(ws + 0);          // 147456 B
  unsigned short* wcimg = (unsigned short*)(ws + 147456);     // 16384 B
  float* x11    = (float*)(ws + 163840);                      // 256 B
  float* x21    = (float*)(ws + 164096);                      // 32768 B
  float* x2mean = (float*)(ws + 196864);                      // 32768 B
  float* hwbuf  = (float*)(ws + 229632);                      // 4 MiB
  float* sigb   = (float*)(ws + 4423936);                     // 4 MiB
  unsigned short* x1buf = (unsigned short*)(ws + 8618240);    // 64 MiB
  unsigned short* x2buf = (unsigned short*)(ws + 75727104);   // 64 MiB
  // xb (bf16 slotted x) lives in d_out: consumed by k_convcat before k_final overwrites d_out
  unsigned short* xb = (unsigned short*)d_out;
  float* out = (float*)d_out;

  hipFuncSetAttribute(reinterpret_cast<const void*>(k_convcat),
                      hipFuncAttributeMaxDynamicSharedMemorySize, 131072);

  k_prep <<<1,    256, 0, stream>>>(w_b1, w_b2, w_cat, gn_b, wimg, wcimg, x11);
  k_rc   <<<1024, 256, 0, stream>>>(x, xb, hwbuf);
  k_hwmm <<<128,  256, 0, stream>>>(hwbuf, w_hw, b_hw, sigb);
  k_gate <<<8192, 256, 0, stream>>>(x, sigb, gn_w, gn_b, x1buf);
  hipMemsetAsync(x2mean, 0, 32768, stream);
  k_convcat<<<1024, 512, 131072, stream>>>(x, xb, (const char*)wimg, (const char*)wcimg,
                                           b_b1, b_b2, a_b1, a_b2, b_cat, x2buf, x2mean);
  k_x21s <<<128,  64, 0, stream>>>(x2mean, b_cat, x21);
  k_final<<<512,  256, 0, stream>>>(x, x1buf, x2buf, x11, x21, out);
}

// Round 4
// 372.705 us; speedup vs baseline: 1.0230x; 1.0230x over previous
//
#include <hip/hip_runtime.h>
#include <hip/hip_bf16.h>

#define HWPX 4096

typedef __attribute__((ext_vector_type(8))) short short8v;
typedef __attribute__((ext_vector_type(4))) float f32x4;
#define MFMA(a,b,c) __builtin_amdgcn_mfma_f32_16x16x32_bf16(a,b,c,0,0,0)

__device__ __forceinline__ float sigf(float x){ return 1.0f/(1.0f+__expf(-x)); }
__device__ __forceinline__ unsigned short f2bf(float f){
  __hip_bfloat16 h = __float2bfloat16(f);
  unsigned short u; __builtin_memcpy(&u, &h, sizeof(u)); return u;
}
__device__ __forceinline__ float bf2f(unsigned short u){
  return __uint_as_float(((unsigned)u)<<16);
}
__device__ __forceinline__ void gl2lds16(const void* g, void* l){
  __builtin_amdgcn_global_load_lds((const __attribute__((address_space(1))) void*)g,
                                   (__attribute__((address_space(3))) void*)l, 16, 0, 0);
}

// ---------------- K0: weight images (bf16) + x11 = softmax(gn_b) ----------------
// wimg: [q2][conv2][tap9][co64][ci32] bf16 ; wcimg: [o64][ch128] bf16
__global__ __launch_bounds__(256) void k_prep(const float* wb1, const float* wb2,
                                              const float* wcat, const float* gnb,
                                              unsigned short* wimg, unsigned short* wcimg,
                                              float* x11){
  int tid = threadIdx.x;
  for (int idx = tid; idx < 73728; idx += 256){
    int q    = idx / 36864;
    int rem  = idx % 36864;
    int conv = rem / 18432;
    int rem2 = rem % 18432;
    int tap  = rem2 / 2048;
    int rem3 = rem2 % 2048;
    int co   = rem3 / 32;
    int cil  = rem3 % 32;
    int ci = q*32 + cil;
    const float* src = conv ? wb2 : wb1;
    float v = src[(co*64 + ci)*9 + tap];
    wimg[((q*18 + conv*9 + tap)*64 + co)*32 + cil] = f2bf(v);
  }
  for (int idx = tid; idx < 8192; idx += 256){
    wcimg[idx] = f2bf(wcat[idx]);
  }
  if (tid < 64){
    float g = gnb[tid];
    float m = g;
    for (int s=32; s; s>>=1) m = fmaxf(m, __shfl_xor(m, s));
    float e = __expf(g-m);
    float se = e;
    for (int s=32; s; s>>=1) se += __shfl_xor(se, s);
    x11[tid] = e/se;
  }
}

// ---------------- K1: x -> bf16 slotted layout xb[g*64+row][slot][col][e8] + row/col means --------
__global__ __launch_bounds__(256) void k_rc(const float* __restrict__ x,
                                            unsigned short* __restrict__ xb,
                                            float* __restrict__ hwbuf){
  int blk = blockIdx.x;          // g*8 + slot
  int g = blk >> 3, slot = blk & 7;
  int tid = threadIdx.x;
  int col = tid & 63, wid = tid >> 6;
  __shared__ float rsm[8*64];
  __shared__ float csm[4*8*64];
  float colacc[8] = {0,0,0,0,0,0,0,0};
  const float* xbase = x + ((size_t)(g*64 + slot*8))*HWPX;
  for (int p=0;p<16;++p){
    int r = wid + 4*p;
    const float* src = xbase + r*64 + col;
    float v[8];
    #pragma unroll
    for (int e=0;e<8;e++) v[e] = src[(size_t)e*HWPX];
    unsigned pk[4];
    #pragma unroll
    for (int j=0;j<4;j++) pk[j] = (unsigned)f2bf(v[2*j]) | ((unsigned)f2bf(v[2*j+1])<<16);
    f32x4 st; __builtin_memcpy(&st, pk, 16);
    *(f32x4*)((char*)xb + (((size_t)(g*64+r))*8 + slot)*1024 + col*16) = st;
    #pragma unroll
    for (int e=0;e<8;e++){
      float s = v[e];
      s += __shfl_xor(s,1); s += __shfl_xor(s,2); s += __shfl_xor(s,4);
      s += __shfl_xor(s,8); s += __shfl_xor(s,16); s += __shfl_xor(s,32);
      if ((tid&63)==0) rsm[e*64+r] = s;
      colacc[e] += v[e];
    }
  }
  #pragma unroll
  for (int e=0;e<8;e++) csm[(wid*8+e)*64+col] = colacc[e];
  __syncthreads();
  float* hb = hwbuf + ((size_t)(g*64 + slot*8))*128;
  for (int idx=tid; idx<512; idx+=256){
    int e = idx>>6, r = idx&63;
    hb[e*128 + r] = rsm[e*64+r] * (1.0f/64.0f);
  }
  for (int idx=tid; idx<512; idx+=256){
    int e = idx>>6, c2 = idx&63;
    float s = csm[(0*8+e)*64+c2] + csm[(1*8+e)*64+c2] + csm[(2*8+e)*64+c2] + csm[(3*8+e)*64+c2];
    hb[e*128 + 64 + c2] = s * (1.0f/64.0f);
  }
}

// ---------------- K2: hw = sigmoid(w_hw @ hw + b_hw) -> sigbuf[bg][o][128] ----------------
__global__ __launch_bounds__(256) void k_hwmm(const float* hwbuf, const float* whw,
                                              const float* bhw, float* sigbuf){
  int g = blockIdx.x;
  __shared__ float hl[64*128];
  int tid = threadIdx.x;
  const float* src = hwbuf + (size_t)g*8192;
  for (int i = tid; i < 2048; i += 256) ((float4*)hl)[i] = ((const float4*)src)[i];
  __syncthreads();
  int p  = tid & 127;
  int o0 = (tid >> 7) * 32;
  float acc[32];
  #pragma unroll
  for (int k=0;k<32;k++) acc[k] = bhw[o0+k];
  for (int i=0;i<64;i++){
    float v = hl[i*128+p];
    #pragma unroll
    for (int k=0;k<32;k++) acc[k] = fmaf(whw[(o0+k)*64+i], v, acc[k]);
  }
  float* dst = sigbuf + (size_t)g*8192;
  #pragma unroll
  for (int k=0;k<32;k++) dst[(o0+k)*128+p] = sigf(acc[k]);
}

// ---------------- K3: gate stats only -> scsh[g][c][2] = (scale, shift) -----------------------
// block = (g, slot): 8 channels; reads bf16 xb coalesced.
__global__ __launch_bounds__(256) void k_gate2(const unsigned short* __restrict__ xb,
                                               const float* __restrict__ sigbuf,
                                               const float* __restrict__ gnw,
                                               const float* __restrict__ gnb,
                                               float* __restrict__ scsh){
  int blk = blockIdx.x;
  int g = blk >> 3, slot = blk & 7;
  int tid = threadIdx.x, col = tid & 63, wq = tid >> 6, lane = tid & 63;
  __shared__ float srm[8*64], scm[8*64], red[4*16];
  for (int idx = tid; idx < 1024; idx += 256){
    int e = idx >> 7, k = idx & 127;
    float v = sigbuf[(size_t)g*8192 + (size_t)(slot*8+e)*128 + k];
    if (k < 64) srm[e*64+k] = v; else scm[e*64+k-64] = v;
  }
  __syncthreads();
  float s[8] = {0,0,0,0,0,0,0,0}, s2[8] = {0,0,0,0,0,0,0,0};
  const char* base = (const char*)xb + (((size_t)(g*64))*8 + slot)*1024;
  for (int p=0;p<16;++p){
    int row = wq*16 + p;
    short8v xv = *(const short8v*)(base + (size_t)row*8192 + col*16);
    #pragma unroll
    for (int e=0;e<8;e++){
      float v = bf2f((unsigned short)xv[e]) * srm[e*64+row] * scm[e*64+col];
      s[e] += v; s2[e] = fmaf(v, v, s2[e]);
    }
  }
  #pragma unroll
  for (int e=0;e<8;e++){
    #pragma unroll
    for (int off=1; off<64; off<<=1){ s[e] += __shfl_xor(s[e], off); s2[e] += __shfl_xor(s2[e], off); }
  }
  if (lane == 0){
    #pragma unroll
    for (int e=0;e<8;e++){ red[wq*16+e] = s[e]; red[wq*16+8+e] = s2[e]; }
  }
  __syncthreads();
  if (tid < 8){
    float S  = red[tid]   + red[16+tid] + red[32+tid] + red[48+tid];
    float S2 = red[8+tid] + red[24+tid] + red[40+tid] + red[56+tid];
    float mu = S*(1.f/4096.f);
    float var = S2*(1.f/4096.f) - mu*mu;
    int c = slot*8 + tid;
    float scale = rsqrtf(var + 1e-5f) * gnw[c];
    scsh[(g*64+c)*2]   = scale;
    scsh[(g*64+c)*2+1] = gnb[c] - mu*scale;
  }
}

// ---------------- K4: fused conv3x3(d1)+conv3x3(d2)+PReLU+residual + 1x1 cat -> wsum2, x2mean ----
// 4-row strips: grid = 128 g * 16 strips; 512 threads; LDS 69632 -> 2 blocks/CU.
__global__ __launch_bounds__(512, 4) void k_convcat(const float* __restrict__ x,
                                                    const unsigned short* __restrict__ xb,
                                                    const char* __restrict__ wgl,
                                                    const char* __restrict__ wcgl,
                                                    const float* __restrict__ bb1,
                                                    const float* __restrict__ bb2,
                                                    const float* __restrict__ a1p,
                                                    const float* __restrict__ a2p,
                                                    const float* __restrict__ bcat,
                                                    const float* __restrict__ x11,
                                                    float* __restrict__ wsum2,
                                                    float* __restrict__ x2mean){
  extern __shared__ char smem[];
  const int tid = threadIdx.x;
  const int g = blockIdx.x >> 4;
  const int strip = blockIdx.x & 15;
  const int r0 = strip*4;
  const int w = tid >> 6;
  const int lane = tid & 63;
  const int l15 = lane & 15;
  const int lg = lane >> 4;
  const int conv = w >> 2;
  const int c0 = (w&3)*16;
  const int dil = conv + 1;

  // zero pad columns {0,1,66,67} of both q buffers (32 segs each)
  if (tid < 256){
    int q = tid >> 7, idx = tid & 127;
    int seg = idx >> 2, p = idx & 3;
    int colp = (p<2) ? p : p+64;
    f32x4 z = {0.f,0.f,0.f,0.f};
    *(f32x4*)(smem + q*34816 + seg*1088 + colp*16) = z;
  }
  // stage both q chunks: 8 rows x 4 slots per q, 1024B segments
  #pragma unroll
  for (int q=0;q<2;++q){
    #pragma unroll
    for (int i=0;i<4;++i){
      int seg = w*4 + i;
      int row = seg >> 2, slot = seg & 3;
      int rg = r0 - 2 + row;
      char* dst = smem + q*34816 + seg*1088 + 32;
      if ((unsigned)rg < 64u){
        const char* src = (const char*)xb + ((((size_t)(g*64+rg))*8 + q*4 + slot)<<10) + lane*16;
        gl2lds16(src, dst);
      } else {
        f32x4 z = {0.f,0.f,0.f,0.f};
        *(f32x4*)(dst + lane*16) = z;
      }
    }
  }

  f32x4 acc[4][4];
  #pragma unroll
  for (int m=0;m<4;m++)
    #pragma unroll
    for (int r=0;r<4;r++)
      acc[m][r] = (f32x4){0.f,0.f,0.f,0.f};

  __syncthreads();

  const int in_lane = lg*1088 + ((c0 + 2 + l15)<<4);
  #pragma unroll
  for (int q=0;q<2;++q){
    const char* inb = smem + q*34816 + in_lane - 32;
    const char* wq = wgl + (size_t)((q*18 + conv*9)*64)*64 + l15*64 + lg*16;
    #pragma unroll
    for (int tap=0;tap<9;++tap){
      const int dy = tap/3 - 1, dx = tap%3 - 1;
      const int off_tap = (dy*dil+2)*4352 + (dx*dil+2)*16;
      const char* wp = wq + tap*4096;
      short8v A0 = *(const short8v*)(wp);
      short8v A1 = *(const short8v*)(wp + 1024);
      short8v A2 = *(const short8v*)(wp + 2048);
      short8v A3 = *(const short8v*)(wp + 3072);
      const char* ib = inb + off_tap;
      #pragma unroll
      for (int r=0;r<4;++r){
        short8v B = *(const short8v*)(ib + r*4352);
        acc[0][r] = MFMA(A0, B, acc[0][r]);
        acc[1][r] = MFMA(A1, B, acc[1][r]);
        acc[2][r] = MFMA(A2, B, acc[2][r]);
        acc[3][r] = MFMA(A3, B, acc[3][r]);
      }
    }
  }
  __syncthreads();

  // epilogue: bias + PReLU + residual(x, f32) -> BR[px256][ch128 swz] bf16
  char* BR = smem;
  {
    const float alpha = conv ? a2p[0] : a1p[0];
    const float* bbp = conv ? bb2 : bb1;
    #pragma unroll
    for (int m=0;m<4;m++){
      int cob = m*16 + lg*4;
      float b0=bbp[cob], b1=bbp[cob+1], b2=bbp[cob+2], b3=bbp[cob+3];
      int ch = conv*64 + cob;
      int slotswz = ((ch>>3) ^ (l15&7)) << 4;
      int bytelo  = (ch&7) << 1;
      const float* resp = x + ((size_t)(g*64 + cob))*HWPX + r0*64 + c0 + l15;
      #pragma unroll
      for (int r=0;r<4;r++){
        float v0 = acc[m][r][0]+b0; v0 = (v0>=0.f? v0 : alpha*v0) + resp[r*64];
        float v1 = acc[m][r][1]+b1; v1 = (v1>=0.f? v1 : alpha*v1) + resp[r*64 + HWPX];
        float v2 = acc[m][r][2]+b2; v2 = (v2>=0.f? v2 : alpha*v2) + resp[r*64 + 2*HWPX];
        float v3 = acc[m][r][3]+b3; v3 = (v3>=0.f? v3 : alpha*v3) + resp[r*64 + 3*HWPX];
        ushort4 pkv; pkv.x=f2bf(v0); pkv.y=f2bf(v1); pkv.z=f2bf(v2); pkv.w=f2bf(v3);
        int pxl = r*64 + c0 + l15;
        *(ushort4*)(BR + pxl*256 + slotswz + bytelo) = pkv;
      }
    }
  }
  __syncthreads();

  // cat 1x1 conv (K=128) -> in-register; reduce to wsum2 (x11-weighted) + x2mean partials
  {
    f32x4 c2[4][2];
    #pragma unroll
    for (int m=0;m<4;m++){ c2[m][0] = (f32x4){0,0,0,0}; c2[m][1] = (f32x4){0,0,0,0}; }

    #pragma unroll
    for (int kc=0;kc<4;kc++){
      short8v Af[4];
      #pragma unroll
      for (int m=0;m<4;m++)
        Af[m] = *(const short8v*)(wcgl + (size_t)((m*16+l15)*128 + kc*32 + lg*8)*2);
      #pragma unroll
      for (int nf=0;nf<2;nf++){
        int pxl = w*32 + nf*16 + l15;
        short8v Bc = *(const short8v*)(BR + pxl*256 + (((kc*4+lg) ^ (l15&7))<<4));
        c2[0][nf] = MFMA(Af[0], Bc, c2[0][nf]);
        c2[1][nf] = MFMA(Af[1], Bc, c2[1][nf]);
        c2[2][nf] = MFMA(Af[2], Bc, c2[2][nf]);
        c2[3][nf] = MFMA(Af[3], Bc, c2[3][nf]);
      }
    }
    float u0 = 0.f, u1 = 0.f;
    #pragma unroll
    for (int m=0;m<4;m++){
      #pragma unroll
      for (int reg=0;reg<4;reg++){
        int o = m*16 + lg*4 + reg;
        float xw = x11[o];
        float bc = bcat[o];
        u0 += xw*(c2[m][0][reg] + bc);
        u1 += xw*(c2[m][1][reg] + bc);
        float sv = c2[m][0][reg] + c2[m][1][reg];
        sv += __shfl_xor(sv,1); sv += __shfl_xor(sv,2);
        sv += __shfl_xor(sv,4); sv += __shfl_xor(sv,8);
        if (l15 == 0) atomicAdd(&x2mean[g*64 + o], sv);
      }
    }
    u0 += __shfl_xor(u0,16); u0 += __shfl_xor(u0,32);
    u1 += __shfl_xor(u1,16); u1 += __shfl_xor(u1,32);
    if (lg == 0){
      float* wp2 = wsum2 + (size_t)g*4096 + strip*256 + w*32 + l15;
      wp2[0]  = u0;
      wp2[16] = u1;
    }
  }
}

// ---------------- K5: x21 = softmax(mean(x2)) from accumulated sums ----------------
__global__ __launch_bounds__(64) void k_x21s(const float* x2mean, const float* bcat, float* x21){
  int g = blockIdx.x;
  int o = threadIdx.x;
  float mean = x2mean[g*64 + o] * (1.f/4096.f) + bcat[o];
  float mx = mean;
  for (int s=32; s; s>>=1) mx = fmaxf(mx, __shfl_xor(mx, s));
  float e = __expf(mean - mx);
  float se = e;
  for (int s=32; s; s>>=1) se += __shfl_xor(se, s);
  x21[g*64 + o] = e/se;
}

// ---------------- K6: W = wsum2 + sum_c x21*x1(recomputed) ; out = x * sigmoid(W) ----------------
__global__ __launch_bounds__(256) void k_final(const float* __restrict__ x,
                                               const float* __restrict__ sigbuf,
                                               const float* __restrict__ scsh,
                                               const float* __restrict__ x21,
                                               const float* __restrict__ wsum2,
                                               float* __restrict__ out){
  int blk = blockIdx.x;                 // g*4 + qr
  int g = blk >> 2, qr = blk & 3;
  int tid = threadIdx.x;
  __shared__ float crow[64*16];
  __shared__ float ccol[64*64];
  __shared__ float shs[64];
  const float* sgb = sigbuf + (size_t)g*8192;
  for (int idx = tid; idx < 1024; idx += 256){
    int c = idx >> 4, r = idx & 15;
    crow[c*16+r] = x21[g*64+c] * scsh[(g*64+c)*2] * sgb[c*128 + qr*16 + r];
  }
  for (int idx = tid; idx < 4096; idx += 256){
    int c = idx >> 6, col = idx & 63;
    ccol[c*64+col] = sgb[c*128 + 64 + col];
  }
  if (tid < 64) shs[tid] = x21[g*64+tid] * scsh[(g*64+tid)*2+1];
  __syncthreads();
  float S = 0.f;
  #pragma unroll
  for (int c=0;c<64;c++) S += shs[c];
  int row = tid >> 4, col0 = (tid & 15)*4;
  int pxg = (qr*16 + row)*64 + col0;
  const float* xp = x + (size_t)(g*64)*HWPX + pxg;
  float4 wv = *(const float4*)(wsum2 + (size_t)g*4096 + pxg);
  float W0 = wv.x + S, W1 = wv.y + S, W2 = wv.z + S, W3 = wv.w + S;
  for (int c=0;c<64;c++){
    float4 xv = *(const float4*)(xp + (size_t)c*HWPX);
    float cr = crow[c*16+row];
    const float* cc = &ccol[c*64+col0];
    W0 = fmaf(cr*cc[0], xv.x, W0);
    W1 = fmaf(cr*cc[1], xv.y, W1);
    W2 = fmaf(cr*cc[2], xv.z, W2);
    W3 = fmaf(cr*cc[3], xv.w, W3);
  }
  float s0 = sigf(W0), s1 = sigf(W1), s2 = sigf(W2), s3 = sigf(W3);
  float* op = out + (size_t)(g*64)*HWPX + pxg;
  for (int c=0;c<64;c++){
    float4 xv = *(const float4*)(xp + (size_t)c*HWPX);
    float4 r4; r4.x = xv.x*s0; r4.y = xv.y*s1; r4.z = xv.z*s2; r4.w = xv.w*s3;
    *(float4*)(op + (size_t)c*HWPX) = r4;
  }
}

extern "C" void kernel_launch(void* const* d_in, const int* in_sizes, int n_in,
                              void* d_out, int out_size, void* d_ws, size_t ws_size,
                              hipStream_t stream) {
  const float* x     = (const float*)d_in[0];
  const float* w_hw  = (const float*)d_in[1];
  const float* b_hw  = (const float*)d_in[2];
  const float* gn_w  = (const float*)d_in[3];
  const float* gn_b  = (const float*)d_in[4];
  const float* w_b1  = (const float*)d_in[5];
  const float* b_b1  = (const float*)d_in[6];
  const float* a_b1  = (const float*)d_in[7];
  const float* w_b2  = (const float*)d_in[8];
  const float* b_b2  = (const float*)d_in[9];
  const float* a_b2  = (const float*)d_in[10];
  const float* w_cat = (const float*)d_in[11];
  const float* b_cat = (const float*)d_in[12];

  char* ws = (char*)d_ws;
  unsigned short* wimg  = (unsigned short*)(ws + 0);          // 147456
  unsigned short* wcimg = (unsigned short*)(ws + 147456);     // 16384
  float* x11    = (float*)(ws + 163840);                      // 256
  float* x21    = (float*)(ws + 164096);                      // 32768
  float* x2mean = (float*)(ws + 196864);                      // 32768
  float* scsh   = (float*)(ws + 229632);                      // 65536
  float* wsum2  = (float*)(ws + 295168);                      // 2097152
  float* hwbuf  = (float*)(ws + 2392320);                     // 4 MiB
  float* sigb   = (float*)(ws + 6586624);                     // 4 MiB
  // xb (bf16 slotted x, 64 MiB) lives in d_out; consumed before k_final overwrites it
  unsigned short* xb = (unsigned short*)d_out;
  float* out = (float*)d_out;

  hipFuncSetAttribute(reinterpret_cast<const void*>(k_convcat),
                      hipFuncAttributeMaxDynamicSharedMemorySize, 69632);

  k_prep <<<1,    256, 0, stream>>>(w_b1, w_b2, w_cat, gn_b, wimg, wcimg, x11);
  k_rc   <<<1024, 256, 0, stream>>>(x, xb, hwbuf);
  k_hwmm <<<128,  256, 0, stream>>>(hwbuf, w_hw, b_hw, sigb);
  k_gate2<<<1024, 256, 0, stream>>>(xb, sigb, gn_w, gn_b, scsh);
  hipMemsetAsync(x2mean, 0, 32768, stream);
  k_convcat<<<2048, 512, 69632, stream>>>(x, xb, (const char*)wimg, (const char*)wcimg,
                                          b_b1, b_b2, a_b1, a_b2, b_cat, x11, wsum2, x2mean);
  k_x21s <<<128,  64, 0, stream>>>(x2mean, b_cat, x21);
  k_final<<<512,  256, 0, stream>>>(x, sigb, scsh, x21, wsum2, out);
}

// Round 5
// 298.415 us; speedup vs baseline: 1.2777x; 1.2489x over previous
//
#include <hip/hip_runtime.h>
#include <hip/hip_bf16.h>

#define HWPX 4096

typedef __attribute__((ext_vector_type(8))) short short8v;
typedef __attribute__((ext_vector_type(4))) float f32x4;
typedef __attribute__((ext_vector_type(16))) float f32x16;
#define MFMA32(a,b,c) __builtin_amdgcn_mfma_f32_32x32x16_bf16(a,b,c,0,0,0)

__device__ __forceinline__ float sigf(float x){ return 1.0f/(1.0f+__expf(-x)); }
__device__ __forceinline__ unsigned short f2bf(float f){
  __hip_bfloat16 h = __float2bfloat16(f);
  unsigned short u; __builtin_memcpy(&u, &h, sizeof(u)); return u;
}
__device__ __forceinline__ float bf2f(unsigned short u){
  return __uint_as_float(((unsigned)u)<<16);
}
__device__ __forceinline__ void gl2lds16(const void* g, void* l){
  __builtin_amdgcn_global_load_lds((const __attribute__((address_space(1))) void*)g,
                                   (__attribute__((address_space(3))) void*)l, 16, 0, 0);
}

// ---------------- K0: fragment-major weight images + x11 = softmax(gn_b) ----------------
// wimg frag f = ((q*2+conv)*9+tap)*4 + kf*2 + cot ; elem = f*512 + lane*8 + j
//   A(co,ci): co = cot*32+(lane&31), ci = q*32+kf*16+(lane>>5)*8+j
// wcimg frag f2 = kfc*2+cot ; o = cot*32+(lane&31), ch = kfc*16+(lane>>5)*8+j
__global__ __launch_bounds__(256) void k_prep(const float* wb1, const float* wb2,
                                              const float* wcat, const float* gnb,
                                              unsigned short* wimg, unsigned short* wcimg,
                                              float* x11){
  int bid = blockIdx.x, tid = threadIdx.x;
  for (int idx = bid*256 + tid; idx < 73728; idx += 64*256){
    int f = idx >> 9, r = idx & 511, lane = r >> 3, j = r & 7;
    int qc = f / 36, rem = f % 36, tap = rem >> 2, kc = rem & 3;
    int q = qc >> 1, conv = qc & 1, kf = kc >> 1, cot = kc & 1;
    int co = cot*32 + (lane & 31);
    int ci = q*32 + kf*16 + (lane >> 5)*8 + j;
    const float* src = conv ? wb2 : wb1;
    wimg[idx] = f2bf(src[(co*64 + ci)*9 + tap]);
  }
  if (bid == 0){
    for (int idx = tid; idx < 8192; idx += 256){
      int f = idx >> 9, r = idx & 511, lane = r >> 3, j = r & 7;
      int kfc = f >> 1, cot = f & 1;
      int o = cot*32 + (lane & 31);
      int ch = kfc*16 + (lane >> 5)*8 + j;
      wcimg[idx] = f2bf(wcat[o*128 + ch]);
    }
    if (tid < 64){
      float g = gnb[tid];
      float m = g;
      for (int s=32; s; s>>=1) m = fmaxf(m, __shfl_xor(m, s));
      float e = __expf(g-m);
      float se = e;
      for (int s=32; s; s>>=1) se += __shfl_xor(se, s);
      x11[tid] = e/se;
    }
  }
}

// ---------------- K1: x -> bf16 slotted layout xb[g*64+row][slot][col][e8] + row/col means --------
__global__ __launch_bounds__(256) void k_rc(const float* __restrict__ x,
                                            unsigned short* __restrict__ xb,
                                            float* __restrict__ hwbuf){
  int blk = blockIdx.x;          // g*8 + slot
  int g = blk >> 3, slot = blk & 7;
  int tid = threadIdx.x;
  int col = tid & 63, wid = tid >> 6;
  __shared__ float rsm[8*64];
  __shared__ float csm[4*8*64];
  float colacc[8] = {0,0,0,0,0,0,0,0};
  const float* xbase = x + ((size_t)(g*64 + slot*8))*HWPX;
  for (int p=0;p<16;++p){
    int r = wid + 4*p;
    const float* src = xbase + r*64 + col;
    float v[8];
    #pragma unroll
    for (int e=0;e<8;e++) v[e] = src[(size_t)e*HWPX];
    unsigned pk[4];
    #pragma unroll
    for (int j=0;j<4;j++) pk[j] = (unsigned)f2bf(v[2*j]) | ((unsigned)f2bf(v[2*j+1])<<16);
    f32x4 st; __builtin_memcpy(&st, pk, 16);
    *(f32x4*)((char*)xb + (((size_t)(g*64+r))*8 + slot)*1024 + col*16) = st;
    #pragma unroll
    for (int e=0;e<8;e++){
      float s = v[e];
      s += __shfl_xor(s,1); s += __shfl_xor(s,2); s += __shfl_xor(s,4);
      s += __shfl_xor(s,8); s += __shfl_xor(s,16); s += __shfl_xor(s,32);
      if ((tid&63)==0) rsm[e*64+r] = s;
      colacc[e] += v[e];
    }
  }
  #pragma unroll
  for (int e=0;e<8;e++) csm[(wid*8+e)*64+col] = colacc[e];
  __syncthreads();
  float* hb = hwbuf + ((size_t)(g*64 + slot*8))*128;
  for (int idx=tid; idx<512; idx+=256){
    int e = idx>>6, r = idx&63;
    hb[e*128 + r] = rsm[e*64+r] * (1.0f/64.0f);
  }
  for (int idx=tid; idx<512; idx+=256){
    int e = idx>>6, c2 = idx&63;
    float s = csm[(0*8+e)*64+c2] + csm[(1*8+e)*64+c2] + csm[(2*8+e)*64+c2] + csm[(3*8+e)*64+c2];
    hb[e*128 + 64 + c2] = s * (1.0f/64.0f);
  }
}

// ---------------- K2: hw = sigmoid(w_hw @ hw + b_hw) -> sigbuf[bg][o][128] ----------------
__global__ __launch_bounds__(256) void k_hwmm(const float* hwbuf, const float* whw,
                                              const float* bhw, float* sigbuf){
  int g = blockIdx.x;
  __shared__ float hl[64*128];
  int tid = threadIdx.x;
  const float* src = hwbuf + (size_t)g*8192;
  for (int i = tid; i < 2048; i += 256) ((float4*)hl)[i] = ((const float4*)src)[i];
  __syncthreads();
  int p  = tid & 127;
  int o0 = (tid >> 7) * 32;
  float acc[32];
  #pragma unroll
  for (int k=0;k<32;k++) acc[k] = bhw[o0+k];
  for (int i=0;i<64;i++){
    float v = hl[i*128+p];
    #pragma unroll
    for (int k=0;k<32;k++) acc[k] = fmaf(whw[(o0+k)*64+i], v, acc[k]);
  }
  float* dst = sigbuf + (size_t)g*8192;
  #pragma unroll
  for (int k=0;k<32;k++) dst[(o0+k)*128+p] = sigf(acc[k]);
}

// ---------------- K3: gate stats -> scsh[g][c][2] = (scale, shift) ----------------
__global__ __launch_bounds__(256) void k_gate2(const unsigned short* __restrict__ xb,
                                               const float* __restrict__ sigbuf,
                                               const float* __restrict__ gnw,
                                               const float* __restrict__ gnb,
                                               float* __restrict__ scsh){
  int blk = blockIdx.x;
  int g = blk >> 3, slot = blk & 7;
  int tid = threadIdx.x, col = tid & 63, wq = tid >> 6, lane = tid & 63;
  __shared__ float srm[8*64], scm[8*64], red[4*16];
  for (int idx = tid; idx < 1024; idx += 256){
    int e = idx >> 7, k = idx & 127;
    float v = sigbuf[(size_t)g*8192 + (size_t)(slot*8+e)*128 + k];
    if (k < 64) srm[e*64+k] = v; else scm[e*64+k-64] = v;
  }
  __syncthreads();
  float s[8] = {0,0,0,0,0,0,0,0}, s2[8] = {0,0,0,0,0,0,0,0};
  const char* base = (const char*)xb + (((size_t)(g*64))*8 + slot)*1024;
  for (int p=0;p<16;++p){
    int row = wq*16 + p;
    short8v xv = *(const short8v*)(base + (size_t)row*8192 + col*16);
    #pragma unroll
    for (int e=0;e<8;e++){
      float v = bf2f((unsigned short)xv[e]) * srm[e*64+row] * scm[e*64+col];
      s[e] += v; s2[e] = fmaf(v, v, s2[e]);
    }
  }
  #pragma unroll
  for (int e=0;e<8;e++){
    #pragma unroll
    for (int off=1; off<64; off<<=1){ s[e] += __shfl_xor(s[e], off); s2[e] += __shfl_xor(s2[e], off); }
  }
  if (lane == 0){
    #pragma unroll
    for (int e=0;e<8;e++){ red[wq*16+e] = s[e]; red[wq*16+8+e] = s2[e]; }
  }
  __syncthreads();
  if (tid < 8){
    float S  = red[tid]   + red[16+tid] + red[32+tid] + red[48+tid];
    float S2 = red[8+tid] + red[24+tid] + red[40+tid] + red[56+tid];
    float mu = S*(1.f/4096.f);
    float var = S2*(1.f/4096.f) - mu*mu;
    int c = slot*8 + tid;
    float scale = rsqrtf(var + 1e-5f) * gnw[c];
    scsh[(g*64+c)*2]   = scale;
    scsh[(g*64+c)*2+1] = gnb[c] - mu*scale;
  }
}

// ---------------- K4: 32x32x16-MFMA conv3x3(d1)+conv3x3(d2)+PReLU+residual + 1x1 cat -------------
// grid = 128 g * 8 strips (8 rows); 512 threads (8 waves: conv = w>>2, ch2 = (w>>1)&1, rquad = w&1)
// LDS: IN[52224] @0 ; W[73728] @52224 ; BR[131072] @0 (epilogue overlay) ; WC[16384] @131072 ;
//      x11/bc @147456 -> total 147968, 1 block/CU.
__global__ __launch_bounds__(512) void k_convcat(const unsigned short* __restrict__ xb,
                                                 const char* __restrict__ wgl,
                                                 const char* __restrict__ wcgl,
                                                 const float* __restrict__ bb1,
                                                 const float* __restrict__ bb2,
                                                 const float* __restrict__ a1p,
                                                 const float* __restrict__ a2p,
                                                 const float* __restrict__ bcat,
                                                 const float* __restrict__ x11,
                                                 float* __restrict__ wsum2,
                                                 float* __restrict__ x2mean){
  extern __shared__ char smem[];
  char* INL = smem;                      // 52224
  char* WL  = smem + 52224;              // 73728
  char* BRL = smem;                      // 131072 (epilogue overlay)
  char* WCL = smem + 131072;             // 16384
  float* x11l = (float*)(smem + 147456); // 64
  float* bcl  = x11l + 64;               // 64

  const int tid = threadIdx.x;
  const int g = blockIdx.x >> 3;
  const int strip = blockIdx.x & 7;
  const int r0 = strip*8;
  const int w = tid >> 6;
  const int lane = tid & 63;
  const int l31 = lane & 31;
  const int lh  = lane >> 5;
  const int conv = w >> 2;
  const int ch2 = (w >> 1) & 1;
  const int rquad = w & 1;
  const int dil = conv + 1;

  // stage wcat fragments (persistent)
  #pragma unroll
  for (int k=0;k<2;k++){
    int idx = tid + k*512;
    gl2lds16(wcgl + (size_t)idx*16, WCL + idx*16);
  }
  if (tid < 64){ x11l[tid] = x11[tid]; bcl[tid] = bcat[tid]; }
  // zero pad cols {0,1,66,67} of IN (once; staging never touches them)
  if (tid < 192){
    int seg = tid >> 2, pc = tid & 3;
    int colp = (pc < 2) ? pc : pc + 64;
    *(f32x4*)(INL + seg*1088 + colp*16) = (f32x4){0.f,0.f,0.f,0.f};
  }

  f32x16 acc[2][4];
  #pragma unroll
  for (int cot=0;cot<2;cot++)
    #pragma unroll
    for (int pt=0;pt<4;pt++)
      #pragma unroll
      for (int e=0;e<16;e++) acc[cot][pt][e] = 0.f;

  const float alpha = conv ? a2p[0] : a1p[0];
  const float* bbp = conv ? bb2 : bb1;

  for (int q=0;q<2;++q){
    if (q) __syncthreads();      // all reads of W/IN from q0 complete before overwrite
    // stage W chunk q (fragment-major, linear): 4608 x 16B
    #pragma unroll
    for (int k=0;k<9;k++){
      int idx = tid + k*512;
      gl2lds16(wgl + (size_t)q*73728 + (size_t)idx*16, WL + idx*16);
    }
    // stage IN chunk q: 48 segs (12 rows x 4 slots)
    #pragma unroll
    for (int i=0;i<6;++i){
      int seg = w*6 + i;
      int row = seg >> 2, slot = seg & 3;
      int rg = r0 - 2 + row;
      char* dst = INL + seg*1088 + 32;
      if ((unsigned)rg < 64u){
        const char* src = (const char*)xb + ((((size_t)(g*64+rg))*8) + q*4 + slot)*1024 + lane*16;
        gl2lds16(src, dst + lane*16);
      } else {
        *(f32x4*)(dst + lane*16) = (f32x4){0.f,0.f,0.f,0.f};
      }
    }
    __syncthreads();
    // MFMA: 9 taps x 2 kf x (2 A ds_reads + 4 x (B ds_read + 2 MFMA))
    #pragma unroll
    for (int tap=0;tap<9;++tap){
      const int dy = tap/3 - 1, dx = tap%3 - 1;
      #pragma unroll
      for (int kf=0;kf<2;++kf){
        const char* wp = WL + (size_t)(((conv*9+tap)*4 + kf*2)*1024) + lane*16;
        short8v A0 = *(const short8v*)(wp);
        short8v A1 = *(const short8v*)(wp + 1024);
        const char* ib = INL + (kf*2 + lh)*1088 + (ch2*32 + 2 + l31 + dx*dil)*16;
        #pragma unroll
        for (int pt=0;pt<4;++pt){
          int rowin = rquad*4 + pt + dy*dil + 2;
          short8v B = *(const short8v*)(ib + rowin*4352);
          acc[0][pt] = MFMA32(A0, B, acc[0][pt]);
          acc[1][pt] = MFMA32(A1, B, acc[1][pt]);
        }
      }
    }
  }
  __syncthreads();

  // epilogue: bias + PReLU + residual (bf16 xb, L2-hot) -> BR swizzled
  #pragma unroll
  for (int cot=0;cot<2;++cot){
    #pragma unroll
    for (int rq=0;rq<4;++rq){
      int co0 = cot*32 + 8*rq + 4*lh;
      float b0 = bbp[co0], b1 = bbp[co0+1], b2 = bbp[co0+2], b3 = bbp[co0+3];
      int ch0 = conv*64 + co0;
      #pragma unroll
      for (int pt=0;pt<4;++pt){
        int prow = rquad*4 + pt;
        int colg = ch2*32 + l31;
        const char* rsrc = (const char*)xb + (((size_t)(g*64 + r0 + prow))*8 + (co0>>3))*1024
                           + colg*16 + (co0&7)*2;
        ushort4 rv = *(const ushort4*)rsrc;
        float v0 = acc[cot][pt][rq*4+0] + b0; v0 = (v0>=0.f? v0 : alpha*v0) + bf2f(rv.x);
        float v1 = acc[cot][pt][rq*4+1] + b1; v1 = (v1>=0.f? v1 : alpha*v1) + bf2f(rv.y);
        float v2 = acc[cot][pt][rq*4+2] + b2; v2 = (v2>=0.f? v2 : alpha*v2) + bf2f(rv.z);
        float v3 = acc[cot][pt][rq*4+3] + b3; v3 = (v3>=0.f? v3 : alpha*v3) + bf2f(rv.w);
        int px = prow*64 + colg;
        int addr = (px*256 + ch0*2) ^ ((px & 15) << 4);
        ushort4 pk; pk.x=f2bf(v0); pk.y=f2bf(v1); pk.z=f2bf(v2); pk.w=f2bf(v3);
        *(ushort4*)(BRL + addr) = pk;
      }
    }
  }
  __syncthreads();

  // cat 1x1 conv (K=128): A from WC frags, B from BR; reduce to wsum2 + x2mean
  {
    f32x16 c2[2][2];
    #pragma unroll
    for (int cot=0;cot<2;cot++)
      #pragma unroll
      for (int t=0;t<2;t++)
        #pragma unroll
        for (int e=0;e<16;e++) c2[cot][t][e] = 0.f;

    #pragma unroll
    for (int kfc=0;kfc<8;++kfc){
      const char* ap = WCL + (size_t)(kfc*2*1024) + lane*16;
      short8v A0 = *(const short8v*)(ap);
      short8v A1 = *(const short8v*)(ap + 1024);
      #pragma unroll
      for (int t=0;t<2;++t){
        int px = w*64 + t*32 + l31;
        int addr = (px*256 + kfc*32 + lh*16) ^ ((px & 15) << 4);
        short8v B = *(const short8v*)(BRL + addr);
        c2[0][t] = MFMA32(A0, B, c2[0][t]);
        c2[1][t] = MFMA32(A1, B, c2[1][t]);
      }
    }
    float u0 = 0.f, u1 = 0.f;
    #pragma unroll
    for (int cot=0;cot<2;++cot){
      #pragma unroll
      for (int reg=0;reg<16;++reg){
        int o = cot*32 + (reg&3) + 8*(reg>>2) + 4*lh;
        float xw = x11l[o], bc = bcl[o];
        u0 += xw*(c2[cot][0][reg] + bc);
        u1 += xw*(c2[cot][1][reg] + bc);
        float sv = c2[cot][0][reg] + c2[cot][1][reg];
        sv += __shfl_xor(sv, 1); sv += __shfl_xor(sv, 2);
        sv += __shfl_xor(sv, 4); sv += __shfl_xor(sv, 8); sv += __shfl_xor(sv, 16);
        if (l31 == 0) atomicAdd(&x2mean[g*64 + o], sv);
      }
    }
    u0 += __shfl_xor(u0, 32);
    u1 += __shfl_xor(u1, 32);
    if (lh == 0){
      float* wp2 = wsum2 + (size_t)g*4096 + strip*512 + w*64 + l31;
      wp2[0]  = u0;
      wp2[32] = u1;
    }
  }
}

// ---------------- K5: x21 = softmax(mean(x2)) ----------------
__global__ __launch_bounds__(64) void k_x21s(const float* x2mean, const float* bcat, float* x21){
  int g = blockIdx.x;
  int o = threadIdx.x;
  float mean = x2mean[g*64 + o] * (1.f/4096.f) + bcat[o];
  float mx = mean;
  for (int s=32; s; s>>=1) mx = fmaxf(mx, __shfl_xor(mx, s));
  float e = __expf(mean - mx);
  float se = e;
  for (int s=32; s; s>>=1) se += __shfl_xor(se, s);
  x21[g*64 + o] = e/se;
}

// ---------------- K6: W = wsum2 + S + sum_c crow*ccol*x ; out = x * sigmoid(W) (one chunk) -------
__global__ __launch_bounds__(256) void k_final(const float* __restrict__ x,
                                               const float* __restrict__ sigbuf,
                                               const float* __restrict__ scsh,
                                               const float* __restrict__ x21,
                                               const float* __restrict__ wsum2,
                                               float* __restrict__ out){
  int blk = blockIdx.x;                 // g*16 + chunk
  int g = blk >> 4, chunk = blk & 15;
  int tid = threadIdx.x;
  __shared__ float crow[64*4];
  __shared__ float ccol[64*64];
  __shared__ float Ssm;
  const float* sgb = sigbuf + (size_t)g*8192;
  {
    int c = tid >> 2, rr = tid & 3;
    crow[tid] = x21[g*64+c] * scsh[(g*64+c)*2] * sgb[c*128 + chunk*4 + rr];
  }
  for (int idx = tid; idx < 4096; idx += 256){
    int c = idx >> 6, col = idx & 63;
    ccol[idx] = sgb[c*128 + 64 + col];
  }
  if (tid < 64){
    float v = x21[g*64+tid] * scsh[(g*64+tid)*2+1];
    for (int s=32; s; s>>=1) v += __shfl_xor(v, s);
    if (tid == 0) Ssm = v;
  }
  __syncthreads();
  int px = chunk*256 + tid;
  int rr = tid >> 6, col = tid & 63;
  const float* xp = x + (size_t)(g*64)*HWPX + px;
  float W = wsum2[(size_t)g*4096 + px] + Ssm;
  #pragma unroll 4
  for (int c=0;c<64;c++){
    W = fmaf(crow[c*4+rr]*ccol[c*64+col], xp[(size_t)c*HWPX], W);
  }
  float s = sigf(W);
  float* op = out + (size_t)(g*64)*HWPX + px;
  #pragma unroll 4
  for (int c=0;c<64;c++){
    op[(size_t)c*HWPX] = xp[(size_t)c*HWPX] * s;
  }
}

extern "C" void kernel_launch(void* const* d_in, const int* in_sizes, int n_in,
                              void* d_out, int out_size, void* d_ws, size_t ws_size,
                              hipStream_t stream) {
  const float* x     = (const float*)d_in[0];
  const float* w_hw  = (const float*)d_in[1];
  const float* b_hw  = (const float*)d_in[2];
  const float* gn_w  = (const float*)d_in[3];
  const float* gn_b  = (const float*)d_in[4];
  const float* w_b1  = (const float*)d_in[5];
  const float* b_b1  = (const float*)d_in[6];
  const float* a_b1  = (const float*)d_in[7];
  const float* w_b2  = (const float*)d_in[8];
  const float* b_b2  = (const float*)d_in[9];
  const float* a_b2  = (const float*)d_in[10];
  const float* w_cat = (const float*)d_in[11];
  const float* b_cat = (const float*)d_in[12];

  char* ws = (char*)d_ws;
  unsigned short* wimg  = (unsigned short*)(ws + 0);          // 147456
  unsigned short* wcimg = (unsigned short*)(ws + 147456);     // 16384
  float* x11    = (float*)(ws + 163840);                      // 256
  float* x21    = (float*)(ws + 164096);                      // 32768
  float* x2mean = (float*)(ws + 196864);                      // 32768
  float* scsh   = (float*)(ws + 229632);                      // 65536
  float* wsum2  = (float*)(ws + 295168);                      // 2097152
  float* hwbuf  = (float*)(ws + 2392320);                     // 4 MiB
  float* sigb   = (float*)(ws + 6586624);                     // 4 MiB
  // xb (bf16 slotted x, 64 MiB) lives in d_out; fully consumed before k_final overwrites it
  unsigned short* xb = (unsigned short*)d_out;
  float* out = (float*)d_out;

  hipFuncSetAttribute(reinterpret_cast<const void*>(k_convcat),
                      hipFuncAttributeMaxDynamicSharedMemorySize, 147968);

  k_prep <<<64,   256, 0, stream>>>(w_b1, w_b2, w_cat, gn_b, wimg, wcimg, x11);
  k_rc   <<<1024, 256, 0, stream>>>(x, xb, hwbuf);
  k_hwmm <<<128,  256, 0, stream>>>(hwbuf, w_hw, b_hw, sigb);
  k_gate2<<<1024, 256, 0, stream>>>(xb, sigb, gn_w, gn_b, scsh);
  hipMemsetAsync(x2mean, 0, 32768, stream);
  k_convcat<<<1024, 512, 147968, stream>>>(xb, (const char*)wimg, (const char*)wcimg,
                                           b_b1, b_b2, a_b1, a_b2, b_cat, x11, wsum2, x2mean);
  k_x21s <<<128,  64, 0, stream>>>(x2mean, b_cat, x21);
  k_final<<<2048, 256, 0, stream>>>(x, sigb, scsh, x21, wsum2, out);
}